// Round 8
// baseline (190.856 us; speedup 1.0000x reference)
//
#include <hip/hip_runtime.h>
#include <hip/hip_bf16.h>

constexpr int BB = 32;     // batches
constexpr int P  = 1024;   // patches per batch
constexpr int O  = 128;    // objects per batch
constexpr int D  = 512;    // feature dim
constexpr float EPS = 1e-8f;
constexpr float SCL = 14.426950408889634f; // (1/0.1) * log2(e)

typedef __attribute__((ext_vector_type(8))) short short8;
typedef __attribute__((ext_vector_type(16))) float f32x16;

__device__ __forceinline__ unsigned short f2bf(float f) {
  __hip_bfloat16 h = __float2bfloat16(f);
  unsigned short u;
  __builtin_memcpy(&u, &h, sizeof(u));
  return u;
}

__device__ __forceinline__ void gld_lds16(const void* g, void* l) {
  __builtin_amdgcn_global_load_lds(
      (const __attribute__((address_space(1))) void*)g,
      (__attribute__((address_space(3))) void*)l, 16, 0, 0);
}

// ---------------- prep: normalized bf16 features into workspace ------------
__global__ __launch_bounds__(256) void prep_kernel(
    const float* __restrict__ pf, const float* __restrict__ of,
    __hip_bfloat16* __restrict__ pn, __hip_bfloat16* __restrict__ on) {
  int lane = threadIdx.x & 63;
  int row = blockIdx.x * 4 + (threadIdx.x >> 6);
  const float* src;
  __hip_bfloat16* dst;
  if (row < BB * P) {
    src = pf + (size_t)row * D;
    dst = pn + (size_t)row * D;
  } else {
    int r = row - BB * P;
    if (r >= BB * O) return;
    src = of + (size_t)r * D;
    dst = on + (size_t)r * D;
  }
  float4 v0 = *(const float4*)(src + lane * 8);
  float4 v1 = *(const float4*)(src + lane * 8 + 4);
  float ss = v0.x * v0.x + v0.y * v0.y + v0.z * v0.z + v0.w * v0.w +
             v1.x * v1.x + v1.y * v1.y + v1.z * v1.z + v1.w * v1.w;
  #pragma unroll
  for (int s = 1; s < 64; s <<= 1) ss += __shfl_xor(ss, s);
  float sc = 1.0f / fmaxf(sqrtf(ss), 1e-12f);
  short8 w;
  w[0] = (short)f2bf(v0.x * sc); w[1] = (short)f2bf(v0.y * sc);
  w[2] = (short)f2bf(v0.z * sc); w[3] = (short)f2bf(v0.w * sc);
  w[4] = (short)f2bf(v1.x * sc); w[5] = (short)f2bf(v1.y * sc);
  w[6] = (short)f2bf(v1.z * sc); w[7] = (short)f2bf(v1.w * sc);
  *reinterpret_cast<short8*>(dst + lane * 8) = w;
}

// ---- main v8: 256x256 patch tiles (8 waves, wave 128x64, acc[4][2]),
// double-buffered LDS, ONE barrier per K-step (stage next || compute cur).
// bid 0..255: object blocks (128x128 tile). bid 256..767: patch blocks.
__global__ __launch_bounds__(512, 2) void icl_main8(
    const __hip_bfloat16* __restrict__ pn, const __hip_bfloat16* __restrict__ on,
    const float* __restrict__ e1i, const float* __restrict__ e1j,
    const float* __restrict__ e2j,
    float* __restrict__ d_row, float* __restrict__ s1_row,
    float* __restrict__ s2_row, unsigned long long* __restrict__ pk_row,
    int* __restrict__ ip_row) {

  // XOR-swizzled row-major [row][64] bf16 tiles: 16B chunk c of row r holds
  // global chunk c^(r&7)  (pre-swizzled global source, linear LDS dest)
  __shared__ __hip_bfloat16 As[2][256 * 64];   // 2 x 32 KB
  __shared__ __hip_bfloat16 Bs[2][256 * 64];   // 2 x 32 KB

  const int tid  = threadIdx.x;
  const int l    = tid & 63;
  const int wid  = tid >> 6;
  const int half = l >> 5;
  const int l31  = l & 31;

  const int bid   = blockIdx.x;
  const bool isobj = bid < 256;

  if (isobj) {
    // ---------------- object blocks: 128 rows x 128 cols ----------------
    const int batch = bid & 31;          // bid%8 == batch%8 -> XCD grouping
    const int rt    = bid >> 5;          // 8 row tiles of 128
    const int row0  = rt * 128;
    const int wr    = wid >> 2;          // rows wr*64
    const int wc    = wid & 3;           // cols wc*32

    const __hip_bfloat16* asrc = pn + (size_t)batch * P * D + (size_t)row0 * D;
    const __hip_bfloat16* bsrc = on + (size_t)batch * O * D;

    f32x16 acc[2];
    #pragma unroll
    for (int m = 0; m < 2; ++m)
      #pragma unroll
      for (int k = 0; k < 16; ++k) acc[m][k] = 0.f;

    auto stage = [&](const __hip_bfloat16* src, __hip_bfloat16* lds, int k0) {
      #pragma unroll
      for (int i = 0; i < 2; ++i) {              // 1024 chunks (128 rows)
        int q = i * 512 + tid;
        int rr = q >> 3, c = q & 7;
        int gc = c ^ (rr & 7);
        gld_lds16(src + (size_t)rr * D + k0 + (gc << 3),
                  (char*)lds + (size_t)(i * 512 + wid * 64) * 16);
      }
    };

    stage(asrc, &As[0][0], 0);
    stage(bsrc, &Bs[0][0], 0);
    __syncthreads();
    int cur = 0;

    for (int ks = 0; ks < 8; ++ks) {
      if (ks < 7) {
        stage(asrc, &As[cur ^ 1][0], (ks + 1) * 64);
        stage(bsrc, &Bs[cur ^ 1][0], (ks + 1) * 64);
      }
      const __hip_bfloat16* ab = &As[cur][0];
      const __hip_bfloat16* bb = &Bs[cur][0];
      #pragma unroll
      for (int kc = 0; kc < 4; ++kc) {
        const int ch = (kc << 1) | half;
        const int bcol = wc * 32 + l31;
        short8 bf = *reinterpret_cast<const short8*>(
            bb + bcol * 64 + ((ch ^ (bcol & 7)) << 3));
        #pragma unroll
        for (int m = 0; m < 2; ++m) {
          int arow = wr * 64 + m * 32 + l31;
          short8 af = *reinterpret_cast<const short8*>(
              ab + arow * 64 + ((ch ^ (arow & 7)) << 3));
          acc[m] = __builtin_amdgcn_mfma_f32_32x32x16_bf16(af, bf, acc[m], 0, 0, 0);
        }
      }
      __syncthreads();   // drains next-tile staging; protects buffer swap
      cur ^= 1;
    }

    // epilogue: delta, s2, one-hot pos, argmax -> atomic combine
    #pragma unroll
    for (int m = 0; m < 2; ++m) {
      #pragma unroll
      for (int r = 0; r < 16; ++r) {
        const int lrow = wr * 64 + m * 32 + (r & 3) + ((r >> 2) << 3) + (half << 2);
        const size_t grow = (size_t)batch * P + row0 + lrow;
        const size_t gb = grow * O;
        const int c0 = wc * 32 + l31;
        float sim = acc[m][r];
        float e = exp2f(sim * SCL);
        float m1 = e1i[gb + c0];
        float m2 = e2j[gb + c0];
        float dv  = m1 * e;
        float s2v = m2 * e;
        int   ipv = (m1 > 0.5f) ? c0 : -1;
        float mvv = sim;
        int   miv = c0;
        #pragma unroll
        for (int s = 1; s < 32; s <<= 1) {
          dv  += __shfl_xor(dv, s);
          s2v += __shfl_xor(s2v, s);
          ipv  = max(ipv, __shfl_xor(ipv, s));
          float ov = __shfl_xor(mvv, s);
          int   oi = __shfl_xor(miv, s);
          if (ov > mvv || (ov == mvv && oi < miv)) { mvv = ov; miv = oi; }
        }
        if (l31 == 0) {
          if (dv != 0.f) atomicAdd(&d_row[grow], dv);
          atomicAdd(&s2_row[grow], s2v);
          unsigned long long pkv =
              ((unsigned long long)__float_as_uint(mvv + 2.0f) << 32) |
              (unsigned)(0xFFFFFFFFu - (unsigned)miv);
          atomicMax(&pk_row[grow], pkv);
          if (ipv >= 0) atomicMax(&ip_row[grow], ipv);
        }
      }
    }
  } else {
    // ---------------- patch blocks: 256 rows x 256 cols ----------------
    const int pid   = bid - 256;
    const int batch = pid & 31;          // bid%8 == batch%8 -> XCD grouping
    const int u     = pid >> 5;          // 0..15
    const int rt    = u & 3;             // 4 row tiles of 256
    const int ct    = u >> 2;            // 4 col tiles of 256
    const int row0  = rt * 256;
    const int pb    = ct * 256;
    const int wr    = wid >> 2;          // rows wr*128 (2 groups)
    const int wcg   = wid & 3;           // cols wcg*64 (4 groups)

    const __hip_bfloat16* pnb  = pn + (size_t)batch * P * D;
    const __hip_bfloat16* asrc = pnb + (size_t)row0 * D;
    const __hip_bfloat16* bsrc = pnb + (size_t)pb * D;

    f32x16 acc[4][2];
    #pragma unroll
    for (int m = 0; m < 4; ++m)
      #pragma unroll
      for (int n = 0; n < 2; ++n)
        #pragma unroll
        for (int k = 0; k < 16; ++k) acc[m][n][k] = 0.f;

    auto stage = [&](const __hip_bfloat16* src, __hip_bfloat16* lds, int k0) {
      #pragma unroll
      for (int i = 0; i < 4; ++i) {              // 2048 chunks (256 rows)
        int q = i * 512 + tid;
        int rr = q >> 3, c = q & 7;
        int gc = c ^ (rr & 7);
        gld_lds16(src + (size_t)rr * D + k0 + (gc << 3),
                  (char*)lds + (size_t)(i * 512 + wid * 64) * 16);
      }
    };

    stage(asrc, &As[0][0], 0);
    stage(bsrc, &Bs[0][0], 0);
    __syncthreads();
    int cur = 0;

    for (int ks = 0; ks < 8; ++ks) {
      if (ks < 7) {
        stage(asrc, &As[cur ^ 1][0], (ks + 1) * 64);
        stage(bsrc, &Bs[cur ^ 1][0], (ks + 1) * 64);
      }
      const __hip_bfloat16* ab = &As[cur][0];
      const __hip_bfloat16* bb = &Bs[cur][0];
      #pragma unroll
      for (int kc = 0; kc < 4; ++kc) {
        const int ch = (kc << 1) | half;
        short8 bf[2];
        #pragma unroll
        for (int n = 0; n < 2; ++n) {
          int bcol = wcg * 64 + n * 32 + l31;
          bf[n] = *reinterpret_cast<const short8*>(
              bb + bcol * 64 + ((ch ^ (bcol & 7)) << 3));
        }
        #pragma unroll
        for (int m = 0; m < 4; ++m) {
          int arow = wr * 128 + m * 32 + l31;
          short8 af = *reinterpret_cast<const short8*>(
              ab + arow * 64 + ((ch ^ (arow & 7)) << 3));
          #pragma unroll
          for (int n = 0; n < 2; ++n)
            acc[m][n] = __builtin_amdgcn_mfma_f32_32x32x16_bf16(
                af, bf[n], acc[m][n], 0, 0, 0);
        }
      }
      __syncthreads();   // drains next-tile staging; protects buffer swap
      cur ^= 1;
    }

    // epilogue: s1 += e1j * pp_exp, row-summed via shuffle, atomic combine
    #pragma unroll
    for (int m = 0; m < 4; ++m) {
      #pragma unroll
      for (int r = 0; r < 16; ++r) {
        const int lrow = wr * 128 + m * 32 + (r & 3) + ((r >> 2) << 3) + (half << 2);
        const size_t grow = (size_t)batch * P + row0 + lrow;
        const size_t gb = grow * P + pb + wcg * 64;
        float v = e1j[gb + l31] * exp2f(acc[m][0][r] * SCL) +
                  e1j[gb + 32 + l31] * exp2f(acc[m][1][r] * SCL);
        #pragma unroll
        for (int s = 1; s < 32; s <<= 1) v += __shfl_xor(v, s);
        if (l31 == 0) atomicAdd(&s1_row[grow], v);
      }
    }
  }
}

// ---------------- per-row loss + scalar reduction --------------------------
__global__ __launch_bounds__(256) void icl_reduce(
    const float* __restrict__ d_row, const float* __restrict__ s1_row,
    const float* __restrict__ s2_row, const unsigned long long* __restrict__ pk_row,
    const int* __restrict__ ip_row, float* __restrict__ accum) {
  __shared__ float red[12];
  const int tid = threadIdx.x;
  const int row = blockIdx.x * 256 + tid;
  float d = d_row[row], a = s1_row[row], c = s2_row[row];
  int ipv = ip_row[row];
  int miv = (int)(0xFFFFFFFFu - (unsigned)(pk_row[row] & 0xFFFFFFFFull));
  float valid = (ipv >= 0) ? 1.f : 0.f;
  float ratio = d / (d + a + c + EPS);
  float lsum = -logf(ratio + EPS) * valid;
  float lbl  = (ipv >= 0 && miv == ipv) ? 1.f : 0.f;
  float vct  = valid;
  #pragma unroll
  for (int s = 1; s < 64; s <<= 1) {
    lsum += __shfl_xor(lsum, s);
    lbl  += __shfl_xor(lbl, s);
    vct  += __shfl_xor(vct, s);
  }
  const int wid = tid >> 6;
  if ((tid & 63) == 0) {
    red[wid * 3 + 0] = lsum;
    red[wid * 3 + 1] = lbl;
    red[wid * 3 + 2] = vct;
  }
  __syncthreads();
  if (tid == 0) {
    atomicAdd(&accum[0], red[0] + red[3] + red[6] + red[9]);
    atomicAdd(&accum[1], red[1] + red[4] + red[7] + red[10]);
    atomicAdd(&accum[2], red[2] + red[5] + red[8] + red[11]);
  }
}

__global__ void finalize_kernel(const float* __restrict__ accum,
                                float* __restrict__ out) {
  if (threadIdx.x == 0 && blockIdx.x == 0) {
    float nv = accum[2];
    out[0] = accum[0] / nv;
    out[1] = accum[1] / nv;
  }
}

// ---------------- fallback path (round-1, known correct) -------------------
__global__ __launch_bounds__(256) void norm_kernel(
    const float* __restrict__ pf, const float* __restrict__ of,
    float* __restrict__ invp, float* __restrict__ invo) {
  int lane = threadIdx.x & 63;
  int row = blockIdx.x * 4 + (threadIdx.x >> 6);
  const float* src;
  float* dst;
  if (row < BB * P) {
    src = pf + (size_t)row * D;
    dst = invp + row;
  } else {
    int r = row - BB * P;
    if (r >= BB * O) return;
    src = of + (size_t)r * D;
    dst = invo + r;
  }
  float ss = 0.f;
  #pragma unroll
  for (int i = 0; i < 2; ++i) {
    float4 v = *(const float4*)(src + (lane + 64 * i) * 4);
    ss += v.x * v.x + v.y * v.y + v.z * v.z + v.w * v.w;
  }
  #pragma unroll
  for (int s = 1; s < 64; s <<= 1) ss += __shfl_xor(ss, s);
  if (lane == 0) *dst = 1.0f / fmaxf(sqrtf(ss), 1e-12f);
}

__global__ __launch_bounds__(256) void icl_main_v1(
    const float* __restrict__ pf, const float* __restrict__ of,
    const float* __restrict__ e1i, const float* __restrict__ e1j,
    const float* __restrict__ e2j, const float* __restrict__ invp,
    const float* __restrict__ invo, float* __restrict__ accum) {
  constexpr int PT = 128, BK = 64;
  __shared__ __hip_bfloat16 As[PT * BK];
  __shared__ __hip_bfloat16 Bs[PT * BK];
  __shared__ float d_l[2][PT], s2_l[2][PT], ei_l[2][PT], s1_l[2][PT], mv_l[2][PT];
  __shared__ int   mi_l[2][PT];
  __shared__ float red[12];

  const int tid  = threadIdx.x;
  const int lane = tid & 63;
  const int wid  = tid >> 6;
  const int wr   = wid >> 1;
  const int wc   = wid & 1;
  const int half = lane >> 5;
  const int l31  = lane & 31;
  const int b    = blockIdx.x & 31;
  const int pt   = blockIdx.x >> 5;
  const int row0 = pt * PT;

  const float* pfb = pf + (size_t)b * P * D;
  const float* ofb = of + (size_t)b * O * D;
  const float* ivp = invp + b * P + row0;
  const float* ivq = invp + b * P;
  const float* ivo = invo + b * O;

  float s1p[2][16];
  #pragma unroll
  for (int m = 0; m < 2; ++m)
    #pragma unroll
    for (int r = 0; r < 16; ++r) s1p[m][r] = 0.f;

  auto stage = [&](const float* __restrict__ src, const float* __restrict__ inv,
                   __hip_bfloat16* __restrict__ lds, int k0) {
    #pragma unroll
    for (int i = 0; i < 8; ++i) {
      int c = i * 256 + tid;
      int rr = c >> 4, kc = c & 15;
      float4 v = *(const float4*)(src + (size_t)rr * D + k0 + (kc << 2));
      float s = inv[rr];
      int off = rr * BK + ((((kc >> 1) ^ (rr & 7)) << 3) | ((kc & 1) << 2));
      ushort4 w;
      w.x = f2bf(v.x * s);
      w.y = f2bf(v.y * s);
      w.z = f2bf(v.z * s);
      w.w = f2bf(v.w * s);
      *reinterpret_cast<ushort4*>(lds + off) = w;
    }
  };

  for (int ct = 0; ct < 9; ++ct) {
    const float* bsrc = (ct == 0) ? ofb : pfb + (size_t)(ct - 1) * 128 * D;
    const float* binv = (ct == 0) ? ivo : ivq + (ct - 1) * 128;

    f32x16 acc[2][2];
    #pragma unroll
    for (int m = 0; m < 2; ++m)
      #pragma unroll
      for (int n = 0; n < 2; ++n)
        #pragma unroll
        for (int k = 0; k < 16; ++k) acc[m][n][k] = 0.f;

    for (int ks = 0; ks < D / BK; ++ks) {
      __syncthreads();
      stage(pfb + (size_t)row0 * D, ivp, As, ks * BK);
      stage(bsrc, binv, Bs, ks * BK);
      __syncthreads();
      #pragma unroll
      for (int kc = 0; kc < 4; ++kc) {
        short8 af[2], bfr[2];
        #pragma unroll
        for (int m = 0; m < 2; ++m) {
          int row = wr * 64 + m * 32 + l31;
          af[m] = *reinterpret_cast<const short8*>(
              As + row * BK + ((((kc << 1) | half) ^ (row & 7)) << 3));
        }
        #pragma unroll
        for (int n = 0; n < 2; ++n) {
          int col = wc * 64 + n * 32 + l31;
          bfr[n] = *reinterpret_cast<const short8*>(
              Bs + col * BK + ((((kc << 1) | half) ^ (col & 7)) << 3));
        }
        #pragma unroll
        for (int m = 0; m < 2; ++m)
          #pragma unroll
          for (int n = 0; n < 2; ++n)
            acc[m][n] = __builtin_amdgcn_mfma_f32_32x32x16_bf16(
                af[m], bfr[n], acc[m][n], 0, 0, 0);
      }
    }

    if (ct == 0) {
      #pragma unroll
      for (int m = 0; m < 2; ++m) {
        #pragma unroll
        for (int r = 0; r < 16; ++r) {
          int lrow = wr * 64 + m * 32 + (r & 3) + ((r >> 2) << 3) + (half << 2);
          size_t base = ((size_t)b * P + row0 + lrow) * O;
          float dsum = 0.f, s2s = 0.f, eis = 0.f, mval = -1e30f;
          int midx = 0;
          #pragma unroll
          for (int n = 0; n < 2; ++n) {
            int col = wc * 64 + n * 32 + l31;
            float sim = acc[m][n][r];
            float e = exp2f(sim * SCL);
            float v1 = e1i[base + col];
            float v2 = e2j[base + col];
            dsum += v1 * e;
            s2s  += v2 * e;
            eis  += v1;
            if (sim > mval) { mval = sim; midx = col; }
          }
          #pragma unroll
          for (int s = 1; s < 32; s <<= 1) {
            dsum += __shfl_xor(dsum, s);
            s2s  += __shfl_xor(s2s, s);
            eis  += __shfl_xor(eis, s);
            float ov = __shfl_xor(mval, s);
            int   oi = __shfl_xor(midx, s);
            if (ov > mval || (ov == mval && oi < midx)) { mval = ov; midx = oi; }
          }
          if (l31 == 0) {
            d_l[wc][lrow] = dsum;
            s2_l[wc][lrow] = s2s;
            ei_l[wc][lrow] = eis;
            mv_l[wc][lrow] = mval;
            mi_l[wc][lrow] = midx;
          }
        }
      }
    } else {
      const int qbase = (ct - 1) * 128;
      #pragma unroll
      for (int m = 0; m < 2; ++m) {
        #pragma unroll
        for (int r = 0; r < 16; ++r) {
          int lrow = wr * 64 + m * 32 + (r & 3) + ((r >> 2) << 3) + (half << 2);
          size_t base = ((size_t)b * P + row0 + lrow) * P + qbase;
          float s = 0.f;
          #pragma unroll
          for (int n = 0; n < 2; ++n) {
            int col = wc * 64 + n * 32 + l31;
            s += e1j[base + col] * exp2f(acc[m][n][r] * SCL);
          }
          s1p[m][r] += s;
        }
      }
    }
  }

  #pragma unroll
  for (int m = 0; m < 2; ++m) {
    #pragma unroll
    for (int r = 0; r < 16; ++r) {
      float v = s1p[m][r];
      #pragma unroll
      for (int s = 1; s < 32; s <<= 1) v += __shfl_xor(v, s);
      if (l31 == 0) {
        int lrow = wr * 64 + m * 32 + (r & 3) + ((r >> 2) << 3) + (half << 2);
        s1_l[wc][lrow] = v;
      }
    }
  }
  __syncthreads();

  float lsum = 0.f, lbl = 0.f, vct = 0.f;
  if (tid < PT) {
    float delta = d_l[0][tid] + d_l[1][tid];
    float s2 = s2_l[0][tid] + s2_l[1][tid];
    float eis = ei_l[0][tid] + ei_l[1][tid];
    float s1 = s1_l[0][tid] + s1_l[1][tid];
    float m0 = mv_l[0][tid], m1 = mv_l[1][tid];
    int mi = (m1 > m0) ? mi_l[1][tid] : mi_l[0][tid];
    float valid = (eis > 0.f) ? 1.f : 0.f;
    float ratio = delta / (delta + s1 + s2 + EPS);
    float loss = -logf(ratio + EPS);
    float label = e1i[((size_t)b * P + row0 + tid) * O + mi];
    lsum = loss * valid;
    lbl  = label * valid;
    vct  = valid;
  }
  #pragma unroll
  for (int s = 1; s < 64; s <<= 1) {
    lsum += __shfl_xor(lsum, s);
    lbl  += __shfl_xor(lbl, s);
    vct  += __shfl_xor(vct, s);
  }
  if (lane == 0) {
    red[wid * 3 + 0] = lsum;
    red[wid * 3 + 1] = lbl;
    red[wid * 3 + 2] = vct;
  }
  __syncthreads();
  if (tid == 0) {
    float a = red[0] + red[3] + red[6] + red[9];
    float c = red[1] + red[4] + red[7] + red[10];
    float v = red[2] + red[5] + red[8] + red[11];
    atomicAdd(&accum[0], a);
    atomicAdd(&accum[1], c);
    atomicAdd(&accum[2], v);
  }
}

extern "C" void kernel_launch(void* const* d_in, const int* in_sizes, int n_in,
                              void* d_out, int out_size, void* d_ws, size_t ws_size,
                              hipStream_t stream) {
  const float* pf  = (const float*)d_in[0];
  const float* of  = (const float*)d_in[1];
  const float* e1i = (const float*)d_in[2];
  const float* e1j = (const float*)d_in[3];
  const float* e2j = (const float*)d_in[4];

  char* base = (char*)d_ws;
  constexpr size_t NR = (size_t)BB * P;               // 32768 rows
  float* accum                 = (float*)base;                    // 64 B
  float* d_row                 = (float*)(base + 64);
  float* s1_row                = (float*)(base + 64 + 4 * NR);
  float* s2_row                = (float*)(base + 64 + 8 * NR);
  unsigned long long* pk_row   = (unsigned long long*)(base + 64 + 12 * NR);
  int* ip_row                  = (int*)(base + 64 + 20 * NR);
  __hip_bfloat16* pn           = (__hip_bfloat16*)(base + 64 + 24 * NR);
  const size_t pn_bytes = (size_t)BB * P * D * 2;
  const size_t on_bytes = (size_t)BB * O * D * 2;
  __hip_bfloat16* on           = (__hip_bfloat16*)(base + 64 + 24 * NR + pn_bytes);
  const size_t need = 64 + 24 * NR + pn_bytes + on_bytes;

  if (ws_size >= need) {
    hipMemsetAsync(base, 0, 64 + 20 * NR, stream);        // accum,d,s1,s2,pk
    hipMemsetAsync(ip_row, 0xFF, 4 * NR, stream);         // ip = -1
    prep_kernel<<<(BB * P + BB * O) / 4, 256, 0, stream>>>(pf, of, pn, on);
    icl_main8<<<768, 512, 0, stream>>>(pn, on, e1i, e1j, e2j,
                                       d_row, s1_row, s2_row, pk_row, ip_row);
    icl_reduce<<<NR / 256, 256, 0, stream>>>(d_row, s1_row, s2_row, pk_row,
                                             ip_row, accum);
  } else {
    float* ws   = (float*)d_ws;
    float* invp = ws + 16;
    float* invo = ws + 16 + BB * P;
    hipMemsetAsync(accum, 0, 16 * sizeof(float), stream);
    norm_kernel<<<(BB * P + BB * O) / 4, 256, 0, stream>>>(pf, of, invp, invo);
    icl_main_v1<<<BB * (P / 128), 256, 0, stream>>>(pf, of, e1i, e1j, e2j,
                                                    invp, invo, accum);
  }
  finalize_kernel<<<1, 64, 0, stream>>>(accum, (float*)d_out);
}